// Round 4
// baseline (260.044 us; speedup 1.0000x reference)
//
#include <hip/hip_runtime.h>
#include <hip/hip_bf16.h>

static constexpr int HEADS = 4;
static constexpr int HID   = 64;
static constexpr int HC    = 256;   // HEADS*HID
static constexpr int NCLS  = 10;

typedef short bf16x8 __attribute__((ext_vector_type(8)));
typedef float f32x4  __attribute__((ext_vector_type(4)));

__device__ inline unsigned short f2bf(float f) {
    union { float f; unsigned u; } c; c.f = f;
    unsigned r = (c.u + 0x7fff + ((c.u >> 16) & 1)) >> 16;  // RNE
    return (unsigned short)r;
}
__device__ inline float bf2f(unsigned short u) {
    union { unsigned u; float f; } c; c.u = ((unsigned)u) << 16; return c.f;
}

// ------------------------------------------------------------------ prep ----
// block 0: cE[h] = sum_k We[h*64+k]*attE[h*64+k]
// blocks 1..256: Wt[n][k] = bf16(W[k][n])   (k = blockIdx-1)
// blocks 257..266: fcWt[j][c] = fcW[c][j]
__global__ void prep_kernel(const float* __restrict__ We, const float* __restrict__ attE,
                            float* __restrict__ cE, const float* __restrict__ W,
                            unsigned short* __restrict__ Wt, const float* __restrict__ fcW,
                            float* __restrict__ fcWt) {
    int b = blockIdx.x, t = threadIdx.x;
    if (b == 0) {
        float p = We[t] * attE[t];
#pragma unroll
        for (int d = 32; d; d >>= 1) p += __shfl_xor(p, d, 64);
        if ((t & 63) == 0) cE[t >> 6] = p;
    } else if (b <= 256) {
        int k = b - 1;
        Wt[t * 256 + k] = f2bf(W[k * 256 + t]);
    } else {
        int j = b - 257;
        fcWt[j * HC + t] = fcW[t * NCLS + j];
    }
}

// ------------------------------------------------------------ MFMA GEMM -----
// XHb[M,256](bf16) = X[M,256](f32) @ Wt^T; A converted fp32->bf16 in staging.
__global__ __launch_bounds__(256) void gemm_mfma(const float* __restrict__ X,
                                                 const unsigned short* __restrict__ Bt,
                                                 unsigned short* __restrict__ XHb, int M) {
    __shared__ alignas(16) unsigned short As[128][40];
    __shared__ alignas(16) unsigned short Bs[128][40];  // Bs[col][k]
    const int tid = threadIdx.x;
    const int lane = tid & 63, wid = tid >> 6;
    const int wr = wid >> 1, wc = wid & 1;
    const int bm = blockIdx.x * 128, bn = blockIdx.y * 128;
    const int fr = lane & 15, kg = lane >> 4;

    f32x4 acc[4][4] = {};

    for (int k0 = 0; k0 < 256; k0 += 32) {
        __syncthreads();
#pragma unroll
        for (int ss = 0; ss < 4; ++ss) {
            int idx = tid + (ss << 8);
            int row = idx >> 3, seg = idx & 7;
            int grow = bm + row;
            float4 av = make_float4(0.f, 0.f, 0.f, 0.f);
            if (grow < M) av = *(const float4*)&X[(size_t)grow * 256 + k0 + seg * 4];
            ushort4 ab = make_ushort4(f2bf(av.x), f2bf(av.y), f2bf(av.z), f2bf(av.w));
            *(ushort4*)&As[row][seg * 4] = ab;
        }
#pragma unroll
        for (int qq = 0; qq < 2; ++qq) {
            int q = tid + (qq << 8);
            int row = q >> 2, part = q & 3;
            const ushort4* bp = (const ushort4*)&Bt[(size_t)(bn + row) * 256 + k0 + part * 8];
            *(ushort4*)&Bs[row][part * 8]     = bp[0];
            *(ushort4*)&Bs[row][part * 8 + 4] = bp[1];
        }
        __syncthreads();

        bf16x8 af[4], bf[4];
#pragma unroll
        for (int i = 0; i < 4; ++i)
            af[i] = *(const bf16x8*)&As[wr * 64 + i * 16 + fr][kg * 8];
#pragma unroll
        for (int j = 0; j < 4; ++j)
            bf[j] = *(const bf16x8*)&Bs[wc * 64 + j * 16 + fr][kg * 8];
#pragma unroll
        for (int i = 0; i < 4; ++i)
#pragma unroll
            for (int j = 0; j < 4; ++j)
                acc[i][j] = __builtin_amdgcn_mfma_f32_16x16x32_bf16(af[i], bf[j], acc[i][j], 0, 0, 0);
    }

    // C/D layout: col = lane&15, row = (lane>>4)*4 + reg
#pragma unroll
    for (int i = 0; i < 4; ++i) {
#pragma unroll
        for (int j = 0; j < 4; ++j) {
            int col = bn + wc * 64 + j * 16 + fr;
#pragma unroll
            for (int r = 0; r < 4; ++r) {
                int row = bm + wr * 64 + i * 16 + kg * 4 + r;
                if (row < M) XHb[(size_t)row * 256 + col] = f2bf(acc[i][j][r]);
            }
        }
    }
}

// ------------------------------------------------------- a_src / a_dst ------
__global__ __launch_bounds__(256) void attn_coef(const unsigned short* __restrict__ xhb,
                                                 const float* __restrict__ attS,
                                                 const float* __restrict__ attD,
                                                 float* __restrict__ a_src,
                                                 float* __restrict__ a_dst,
                                                 int Nn) {
    int wid = threadIdx.x >> 6, lane = threadIdx.x & 63;
    int n = blockIdx.x * 4 + wid;
    if (n >= Nn) return;
    ushort4 xv = *(const ushort4*)&xhb[(size_t)n * HC + lane * 4];
    float x0 = bf2f(xv.x), x1 = bf2f(xv.y), x2 = bf2f(xv.z), x3 = bf2f(xv.w);
    float4 sv = *(const float4*)&attS[lane * 4];
    float4 dv = *(const float4*)&attD[lane * 4];
    float ps = x0 * sv.x + x1 * sv.y + x2 * sv.z + x3 * sv.w;
    float pd = x0 * dv.x + x1 * dv.y + x2 * dv.z + x3 * dv.w;
#pragma unroll
    for (int d = 1; d < 16; d <<= 1) {
        ps += __shfl_xor(ps, d, 64);
        pd += __shfl_xor(pd, d, 64);
    }
    if ((lane & 15) == 0) {
        a_src[n * 4 + (lane >> 4)] = ps;
        a_dst[n * 4 + (lane >> 4)] = pd;
    }
}

// ------------------------------------------------------------- CSR build ----
__global__ void hist_kernel(const int* __restrict__ dst, int* __restrict__ deg, int E) {
    int e = blockIdx.x * 256 + threadIdx.x;
    if (e < E) atomicAdd(&deg[dst[e]], 1);
}

// scan of PADDED degrees (each deg rounded up to x16)
__global__ __launch_bounds__(1024) void scan1(const int* __restrict__ deg,
                                              int* __restrict__ row_start,
                                              int* __restrict__ bsum, int n) {
    __shared__ int wsum[16];
    const int tid = threadIdx.x, lane = tid & 63, wid = tid >> 6;
    int i = blockIdx.x * 1024 + tid;
    int v = (i < n) ? ((deg[i] + 15) & ~15) : 0;
    int incl = v;
#pragma unroll
    for (int d = 1; d < 64; d <<= 1) {
        int t = __shfl_up(incl, d, 64);
        if (lane >= d) incl += t;
    }
    if (lane == 63) wsum[wid] = incl;
    __syncthreads();
    if (tid < 16) {
        int w = wsum[tid];
#pragma unroll
        for (int d = 1; d < 16; d <<= 1) {
            int t = __shfl_up(w, d, 16);
            if (tid >= d) w += t;
        }
        wsum[tid] = w;
    }
    __syncthreads();
    int waveoff = wid ? wsum[wid - 1] : 0;
    if (i < n) row_start[i] = waveoff + incl - v;
    if (tid == 1023) bsum[blockIdx.x] = waveoff + incl;
}

// fused scan2+scan3: every block scans the <=64 block sums redundantly,
// adds its prefix, writes final row_start and the scatter cursor copy.
__global__ __launch_bounds__(1024) void scan23(int* __restrict__ row_start,
                                               const int* __restrict__ bsum,
                                               int* __restrict__ cursor, int n, int nb) {
    __shared__ int pref[64];
    const int tid = threadIdx.x;
    if (tid < 64) {
        int v = (tid < nb) ? bsum[tid] : 0;
#pragma unroll
        for (int d = 1; d < 64; d <<= 1) {
            int t = __shfl_up(v, d, 64);
            if (tid >= d) v += t;
        }
        pref[tid] = v;
    }
    __syncthreads();
    int add = blockIdx.x ? pref[blockIdx.x - 1] : 0;
    int i = blockIdx.x * 1024 + tid;
    if (i < n) {
        int v = row_start[i] + add;
        row_start[i] = v;
        cursor[i] = v;
    }
    if (i == n) row_start[n] = pref[nb - 1];
}

// ------------------------------------------------------------ scatter+p -----
// Per edge: compute p[h] = exp(leakyrelu(a_src[s]+a_dst[d]+cE[h]*w)) and
// scatter {src, p0..p3} into the padded CSR slot (atomic ticket).
__global__ void scatter_p(const int* __restrict__ src, const int* __restrict__ dst,
                          const float* __restrict__ ew, const float* __restrict__ a_src,
                          const float* __restrict__ a_dst, const float* __restrict__ cE,
                          int* __restrict__ cursor, int* __restrict__ src_s,
                          float* __restrict__ p_t, int E, int Ep) {
    int e = blockIdx.x * 256 + threadIdx.x;
    if (e >= E) return;
    int s = src[e], d = dst[e];
    float w = ew[e];
    float4 as_ = *(const float4*)&a_src[s * 4];
    float4 ad_ = *(const float4*)&a_dst[d * 4];
    float4 ce  = *(const float4*)cE;
    int pos = atomicAdd(&cursor[d], 1);
    src_s[pos] = s;
    float al[4] = {as_.x + ad_.x + ce.x * w, as_.y + ad_.y + ce.y * w,
                   as_.z + ad_.z + ce.z * w, as_.w + ad_.w + ce.w * w};
#pragma unroll
    for (int h = 0; h < 4; ++h) {
        float a = al[h] > 0.f ? al[h] : 0.2f * al[h];
        p_t[h * Ep + pos] = __expf(a);     // no max-sub: |alpha| small
    }
}

// ------------------------------------------------------------- main GAT -----
// One WAVE per node. Lane l owns channels 4l..4l+3 (head myh=l>>4).
// Chunks of 16 padded edges: p from per-head planes (identical within a
// 16-lane group -> esum needs NO reduction), src via readlane -> scalar-base
// row gathers. Pads have p=0, src=0.
__global__ __launch_bounds__(256) void gat_main(
    const unsigned short* __restrict__ xhb, const int* __restrict__ row_start,
    const int* __restrict__ src_s, const float* __restrict__ p_t,
    const float* __restrict__ bias, const float* __restrict__ gamma,
    const float* __restrict__ beta, const float* __restrict__ fcWt,
    const float* __restrict__ fcb, float* __restrict__ out, int Nn, int Ep) {
    const int lane = threadIdx.x & 63, wid = threadIdx.x >> 6;
    const int n = blockIdx.x * 4 + wid;
    if (n >= Nn) return;
    const int myh = lane >> 4;
    const int rs = row_start[n], re = row_start[n + 1];
    const float* pplane = p_t + (size_t)myh * Ep;

    f32x4 acc = {0.f, 0.f, 0.f, 0.f};
    float psum = 0.f;

    for (int e0 = rs; e0 < re; e0 += 16) {
        int sv = src_s[e0 + (lane & 15)];
        float4 pa = *(const float4*)&pplane[e0];
        float4 pb = *(const float4*)&pplane[e0 + 4];
        float4 pc = *(const float4*)&pplane[e0 + 8];
        float4 pd = *(const float4*)&pplane[e0 + 12];
        float pv[16] = {pa.x, pa.y, pa.z, pa.w, pb.x, pb.y, pb.z, pb.w,
                        pc.x, pc.y, pc.z, pc.w, pd.x, pd.y, pd.z, pd.w};
        psum += ((pa.x + pa.y) + (pa.z + pa.w)) + ((pb.x + pb.y) + (pb.z + pb.w)) +
                ((pc.x + pc.y) + (pc.z + pc.w)) + ((pd.x + pd.y) + (pd.z + pd.w));
#pragma unroll
        for (int ee = 0; ee < 16; ++ee) {
            int sb = __builtin_amdgcn_readlane(sv, ee);   // SGPR row index
            const ushort4* rp = (const ushort4*)(xhb + (size_t)sb * HC);
            ushort4 xv = rp[lane];                        // s-base + lane offset
            float p = pv[ee];
            acc[0] = fmaf(p, bf2f(xv.x), acc[0]);
            acc[1] = fmaf(p, bf2f(xv.y), acc[1]);
            acc[2] = fmaf(p, bf2f(xv.z), acc[2]);
            acc[3] = fmaf(p, bf2f(xv.w), acc[3]);
        }
    }

    // every lane of a head-group already holds the full per-head sum
    float rin = 1.f / (psum + 1e-16f);

    float4 bv = *(const float4*)&bias[lane * 4];
    float v0 = acc[0] * rin + bv.x;
    float v1 = acc[1] * rin + bv.y;
    float v2 = acc[2] * rin + bv.z;
    float v3 = acc[3] * rin + bv.w;

    // LayerNorm over 256 channels (wave-wide reduce)
    float s1 = v0 + v1 + v2 + v3;
    float s2 = v0 * v0 + v1 * v1 + v2 * v2 + v3 * v3;
#pragma unroll
    for (int d = 1; d < 64; d <<= 1) {
        s1 += __shfl_xor(s1, d, 64);
        s2 += __shfl_xor(s2, d, 64);
    }
    float mu = s1 * (1.f / 256.f);
    float var = s2 * (1.f / 256.f) - mu * mu;
    float rstd = rsqrtf(var + 1e-5f);
    float4 gv = *(const float4*)&gamma[lane * 4];
    float4 btv = *(const float4*)&beta[lane * 4];
    float y0 = fmaxf((v0 - mu) * rstd * gv.x + btv.x, 0.f);
    float y1 = fmaxf((v1 - mu) * rstd * gv.y + btv.y, 0.f);
    float y2 = fmaxf((v2 - mu) * rstd * gv.z + btv.z, 0.f);
    float y3 = fmaxf((v3 - mu) * rstd * gv.w + btv.w, 0.f);

    // FC 256 -> 10
    float keep = 0.f;
#pragma unroll
    for (int j = 0; j < NCLS; ++j) {
        float4 wv = *(const float4*)&fcWt[j * HC + lane * 4];
        float pj = y0 * wv.x;
        pj = fmaf(y1, wv.y, pj);
        pj = fmaf(y2, wv.z, pj);
        pj = fmaf(y3, wv.w, pj);
#pragma unroll
        for (int d = 1; d < 64; d <<= 1) pj += __shfl_xor(pj, d, 64);
        if (lane == j) keep = pj + fcb[j];
    }
    if (lane < NCLS) out[n * NCLS + lane] = keep;
}

// ---------------------------------------------------------------- launch ----
extern "C" void kernel_launch(void* const* d_in, const int* in_sizes, int n_in,
                              void* d_out, int out_size, void* d_ws, size_t ws_size,
                              hipStream_t stream) {
    const float* x    = (const float*)d_in[0];
    const int*   ei   = (const int*)d_in[1];
    const float* ew   = (const float*)d_in[2];
    const float* W    = (const float*)d_in[3];
    const float* attS = (const float*)d_in[4];
    const float* attD = (const float*)d_in[5];
    const float* attE = (const float*)d_in[6];
    const float* We   = (const float*)d_in[7];
    const float* bias = (const float*)d_in[8];
    const float* gam  = (const float*)d_in[9];
    const float* bet  = (const float*)d_in[10];
    const float* fcW  = (const float*)d_in[11];
    const float* fcb  = (const float*)d_in[12];
    float* out = (float*)d_out;

    const int Nn = in_sizes[0] / HC;       // 50000
    const int E  = in_sizes[1] / 2;        // 800000
    const int* src = ei;
    const int* dst = ei + E;
    const int nb = (Nn + 1023) / 1024;     // 49
    const int Ep = (E + 16 * Nn + 15) & ~15;  // worst-case padded slots

    char* ws = (char*)d_ws;
    size_t off = 0;
    auto alloc = [&](size_t bytes) { void* p = ws + off; off = (off + bytes + 255) & ~size_t(255); return p; };
    unsigned short* xhb  = (unsigned short*)alloc((size_t)Nn * HC * 2);
    unsigned short* wt   = (unsigned short*)alloc((size_t)HC * HC * 2);
    float* a_srcb    = (float*)alloc((size_t)Nn * 4 * 4);
    float* a_dstb    = (float*)alloc((size_t)Nn * 4 * 4);
    float* cE        = (float*)alloc(256);
    float* fcWt      = (float*)alloc((size_t)NCLS * HC * 4);
    int*   row_start = (int*)  alloc((size_t)(Nn + 1) * 4);
    int*   deg       = (int*)  alloc((size_t)Nn * 4);
    int*   cursor    = (int*)  alloc((size_t)Nn * 4);
    int*   bsum      = (int*)  alloc((size_t)nb * 4);
    int*   src_s     = (int*)  alloc((size_t)Ep * 4);       // contiguous with p_t
    float* p_t       = (float*)alloc((size_t)Ep * 4 * 4);   // 4 head planes
    (void)ws_size;

    hipMemsetAsync(deg, 0, (size_t)Nn * 4, stream);
    // zero src_s + p_t together (pads must read as src=0, p=0)
    hipMemsetAsync(src_s, 0, (size_t)Ep * 4 + ((size_t)p_t - (size_t)src_s - (size_t)Ep * 4) + (size_t)Ep * 16, stream);

    prep_kernel<<<267, 256, 0, stream>>>(We, attE, cE, W, wt, fcW, fcWt);

    dim3 g((Nn + 127) / 128, 2);
    gemm_mfma<<<g, 256, 0, stream>>>(x, wt, xhb, Nn);

    attn_coef<<<(Nn + 3) / 4, 256, 0, stream>>>(xhb, attS, attD, a_srcb, a_dstb, Nn);
    hist_kernel<<<(E + 255) / 256, 256, 0, stream>>>(dst, deg, E);
    scan1<<<nb, 1024, 0, stream>>>(deg, row_start, bsum, Nn);
    scan23<<<nb, 1024, 0, stream>>>(row_start, bsum, cursor, Nn, nb);
    scatter_p<<<(E + 255) / 256, 256, 0, stream>>>(src, dst, ew, a_srcb, a_dstb, cE,
                                                   cursor, src_s, p_t, E, Ep);
    gat_main<<<(Nn + 3) / 4, 256, 0, stream>>>(xhb, row_start, src_s, p_t,
                                               bias, gam, bet, fcWt, fcb, out, Nn, Ep);
}

// Round 5
// 220.130 us; speedup vs baseline: 1.1813x; 1.1813x over previous
//
#include <hip/hip_runtime.h>
#include <hip/hip_bf16.h>

static constexpr int HEADS = 4;
static constexpr int HID   = 64;
static constexpr int HC    = 256;   // HEADS*HID
static constexpr int NCLS  = 10;

typedef short bf16x8 __attribute__((ext_vector_type(8)));
typedef float f32x4  __attribute__((ext_vector_type(4)));
typedef _Float16 f16x4 __attribute__((ext_vector_type(4)));

__device__ inline unsigned short f2bf(float f) {
    union { float f; unsigned u; } c; c.f = f;
    unsigned r = (c.u + 0x7fff + ((c.u >> 16) & 1)) >> 16;  // RNE
    return (unsigned short)r;
}
__device__ inline unsigned short f2h(float f) {
    _Float16 h = (_Float16)f; unsigned short u; __builtin_memcpy(&u, &h, 2); return u;
}
__device__ inline float h2f(unsigned short u) {
    _Float16 h; __builtin_memcpy(&h, &u, 2); return (float)h;
}

// ------------------------------------------------------------------ prep ----
__global__ void prep_kernel(const float* __restrict__ We, const float* __restrict__ attE,
                            float* __restrict__ cE, const float* __restrict__ W,
                            unsigned short* __restrict__ Wt, const float* __restrict__ fcW,
                            float* __restrict__ fcWt) {
    int b = blockIdx.x, t = threadIdx.x;
    if (b == 0) {
        float p = We[t] * attE[t];
#pragma unroll
        for (int d = 32; d; d >>= 1) p += __shfl_xor(p, d, 64);
        if ((t & 63) == 0) cE[t >> 6] = p;
    } else if (b <= 256) {
        int k = b - 1;
        Wt[t * 256 + k] = f2bf(W[k * 256 + t]);
    } else {
        int j = b - 257;
        fcWt[j * HC + t] = fcW[t * NCLS + j];
    }
}

// ------------------------------------------------------------ MFMA GEMM -----
// XHh[M,256](f16) = X[M,256](f32) @ Wt^T (bf16 MFMA, f16 output).
__global__ __launch_bounds__(256) void gemm_mfma(const float* __restrict__ X,
                                                 const unsigned short* __restrict__ Bt,
                                                 unsigned short* __restrict__ XHh, int M) {
    __shared__ alignas(16) unsigned short As[128][40];
    __shared__ alignas(16) unsigned short Bs[128][40];  // Bs[col][k]
    const int tid = threadIdx.x;
    const int lane = tid & 63, wid = tid >> 6;
    const int wr = wid >> 1, wc = wid & 1;
    const int bm = blockIdx.x * 128, bn = blockIdx.y * 128;
    const int fr = lane & 15, kg = lane >> 4;

    f32x4 acc[4][4] = {};

    for (int k0 = 0; k0 < 256; k0 += 32) {
        __syncthreads();
#pragma unroll
        for (int ss = 0; ss < 4; ++ss) {
            int idx = tid + (ss << 8);
            int row = idx >> 3, seg = idx & 7;
            int grow = bm + row;
            float4 av = make_float4(0.f, 0.f, 0.f, 0.f);
            if (grow < M) av = *(const float4*)&X[(size_t)grow * 256 + k0 + seg * 4];
            ushort4 ab = make_ushort4(f2bf(av.x), f2bf(av.y), f2bf(av.z), f2bf(av.w));
            *(ushort4*)&As[row][seg * 4] = ab;
        }
#pragma unroll
        for (int qq = 0; qq < 2; ++qq) {
            int q = tid + (qq << 8);
            int row = q >> 2, part = q & 3;
            const ushort4* bp = (const ushort4*)&Bt[(size_t)(bn + row) * 256 + k0 + part * 8];
            *(ushort4*)&Bs[row][part * 8]     = bp[0];
            *(ushort4*)&Bs[row][part * 8 + 4] = bp[1];
        }
        __syncthreads();

        bf16x8 af[4], bf[4];
#pragma unroll
        for (int i = 0; i < 4; ++i)
            af[i] = *(const bf16x8*)&As[wr * 64 + i * 16 + fr][kg * 8];
#pragma unroll
        for (int j = 0; j < 4; ++j)
            bf[j] = *(const bf16x8*)&Bs[wc * 64 + j * 16 + fr][kg * 8];
#pragma unroll
        for (int i = 0; i < 4; ++i)
#pragma unroll
            for (int j = 0; j < 4; ++j)
                acc[i][j] = __builtin_amdgcn_mfma_f32_16x16x32_bf16(af[i], bf[j], acc[i][j], 0, 0, 0);
    }

    // C/D layout: col = lane&15, row = (lane>>4)*4 + reg
#pragma unroll
    for (int i = 0; i < 4; ++i) {
#pragma unroll
        for (int j = 0; j < 4; ++j) {
            int col = bn + wc * 64 + j * 16 + fr;
#pragma unroll
            for (int r = 0; r < 4; ++r) {
                int row = bm + wr * 64 + i * 16 + kg * 4 + r;
                if (row < M) XHh[(size_t)row * 256 + col] = f2h(acc[i][j][r]);
            }
        }
    }
}

// ------------------------------------------------------- a_src / a_dst ------
__global__ __launch_bounds__(256) void attn_coef(const unsigned short* __restrict__ xhh,
                                                 const float* __restrict__ attS,
                                                 const float* __restrict__ attD,
                                                 float* __restrict__ a_src,
                                                 float* __restrict__ a_dst,
                                                 int Nn) {
    int wid = threadIdx.x >> 6, lane = threadIdx.x & 63;
    int n = blockIdx.x * 4 + wid;
    if (n >= Nn) return;
    ushort4 xv = *(const ushort4*)&xhh[(size_t)n * HC + lane * 4];
    float x0 = h2f(xv.x), x1 = h2f(xv.y), x2 = h2f(xv.z), x3 = h2f(xv.w);
    float4 sv = *(const float4*)&attS[lane * 4];
    float4 dv = *(const float4*)&attD[lane * 4];
    float ps = x0 * sv.x + x1 * sv.y + x2 * sv.z + x3 * sv.w;
    float pd = x0 * dv.x + x1 * dv.y + x2 * dv.z + x3 * dv.w;
#pragma unroll
    for (int d = 1; d < 16; d <<= 1) {
        ps += __shfl_xor(ps, d, 64);
        pd += __shfl_xor(pd, d, 64);
    }
    if ((lane & 15) == 0) {
        a_src[n * 4 + (lane >> 4)] = ps;
        a_dst[n * 4 + (lane >> 4)] = pd;
    }
}

// ------------------------------------------------------------- CSR build ----
__global__ void hist_kernel(const int* __restrict__ dst, int* __restrict__ deg, int E) {
    int e = blockIdx.x * 256 + threadIdx.x;
    if (e < E) atomicAdd(&deg[dst[e]], 1);
}

// scan of PADDED degrees (each deg rounded up to x4)
__global__ __launch_bounds__(1024) void scan1(const int* __restrict__ deg,
                                              int* __restrict__ row_start,
                                              int* __restrict__ bsum, int n) {
    __shared__ int wsum[16];
    const int tid = threadIdx.x, lane = tid & 63, wid = tid >> 6;
    int i = blockIdx.x * 1024 + tid;
    int v = (i < n) ? ((deg[i] + 3) & ~3) : 0;
    int incl = v;
#pragma unroll
    for (int d = 1; d < 64; d <<= 1) {
        int t = __shfl_up(incl, d, 64);
        if (lane >= d) incl += t;
    }
    if (lane == 63) wsum[wid] = incl;
    __syncthreads();
    if (tid < 16) {
        int w = wsum[tid];
#pragma unroll
        for (int d = 1; d < 16; d <<= 1) {
            int t = __shfl_up(w, d, 16);
            if (tid >= d) w += t;
        }
        wsum[tid] = w;
    }
    __syncthreads();
    int waveoff = wid ? wsum[wid - 1] : 0;
    if (i < n) row_start[i] = waveoff + incl - v;
    if (tid == 1023) bsum[blockIdx.x] = waveoff + incl;
}

// fused scan2+scan3
__global__ __launch_bounds__(1024) void scan23(int* __restrict__ row_start,
                                               const int* __restrict__ bsum,
                                               int* __restrict__ cursor, int n, int nb) {
    __shared__ int pref[64];
    const int tid = threadIdx.x;
    if (tid < 64) {
        int v = (tid < nb) ? bsum[tid] : 0;
#pragma unroll
        for (int d = 1; d < 64; d <<= 1) {
            int t = __shfl_up(v, d, 64);
            if (tid >= d) v += t;
        }
        pref[tid] = v;
    }
    __syncthreads();
    int add = blockIdx.x ? pref[blockIdx.x - 1] : 0;
    int i = blockIdx.x * 1024 + tid;
    if (i < n) {
        int v = row_start[i] + add;
        row_start[i] = v;
        cursor[i] = v;
    }
    if (i == n) row_start[n] = pref[nb - 1];
}

// ------------------------------------------------------------ scatter+p -----
// Per edge: p[h] = exp(leakyrelu(a_src[s]+a_dst[d]+cE[h]*w)), scattered into
// the padded CSR slot. p layout: pq[group][h][4] (group = pos>>2) so one
// edge's 4 p-stores hit ONE 64B line; src on a second line.
__global__ void scatter_p(const int* __restrict__ src, const int* __restrict__ dst,
                          const float* __restrict__ ew, const float* __restrict__ a_src,
                          const float* __restrict__ a_dst, const float* __restrict__ cE,
                          int* __restrict__ cursor, int* __restrict__ srcs,
                          float* __restrict__ pq, int E) {
    int e = blockIdx.x * 256 + threadIdx.x;
    if (e >= E) return;
    int s = src[e], d = dst[e];
    float w = ew[e];
    float4 as_ = *(const float4*)&a_src[s * 4];
    float4 ad_ = *(const float4*)&a_dst[d * 4];
    float4 ce  = *(const float4*)cE;
    int pos = atomicAdd(&cursor[d], 1);
    srcs[pos] = s;
    float al[4] = {as_.x + ad_.x + ce.x * w, as_.y + ad_.y + ce.y * w,
                   as_.z + ad_.z + ce.z * w, as_.w + ad_.w + ce.w * w};
    float* base = pq + ((size_t)(pos >> 2)) * 16 + (pos & 3);
#pragma unroll
    for (int h = 0; h < 4; ++h) {
        float a = al[h] > 0.f ? al[h] : 0.2f * al[h];
        base[h * 4] = __expf(a);           // no max-sub: |alpha| small
    }
}

// ------------------------------------------------------------- main GAT -----
// One WAVE per node. Lane l owns channels 4l..4l+3 (head myh=l>>4).
// 4-edge chunks: src quad broadcast + readfirstlane, p quad per head-group
// (one float4 = the 4 edges' p for this head), prefetch next chunk.
__global__ __launch_bounds__(256) void gat_main(
    const unsigned short* __restrict__ xhh, const int* __restrict__ row_start,
    const int* __restrict__ srcs, const float* __restrict__ pq,
    const float* __restrict__ bias, const float* __restrict__ gamma,
    const float* __restrict__ beta, const float* __restrict__ fcWt,
    const float* __restrict__ fcb, float* __restrict__ out, int Nn) {
    const int lane = threadIdx.x & 63, wid = threadIdx.x >> 6;
    const int n = blockIdx.x * 4 + wid;
    if (n >= Nn) return;
    const int myh = lane >> 4;
    const int rs = row_start[n], re = row_start[n + 1];

    f32x4 acc = {0.f, 0.f, 0.f, 0.f};
    float psum = 0.f;

    if (rs < re) {
        int4   sv = *(const int4*)&srcs[rs];                              // broadcast
        float4 pv = *(const float4*)&pq[((size_t)(rs >> 2)) * 16 + myh * 4];
        for (int e0 = rs; e0 < re; e0 += 4) {
            int e1 = e0 + 4;
            int4 svn = sv; float4 pvn = pv;
            if (e1 < re) {                                                // prefetch
                svn = *(const int4*)&srcs[e1];
                pvn = *(const float4*)&pq[((size_t)(e1 >> 2)) * 16 + myh * 4];
            }
            psum += ((pv.x + pv.y) + (pv.z + pv.w));
            {
                int sb = __builtin_amdgcn_readfirstlane(sv.x);
                f16x4 xv = *(const f16x4*)(xhh + (size_t)sb * HC + lane * 4);
                acc[0] = fmaf(pv.x, (float)xv.x, acc[0]);
                acc[1] = fmaf(pv.x, (float)xv.y, acc[1]);
                acc[2] = fmaf(pv.x, (float)xv.z, acc[2]);
                acc[3] = fmaf(pv.x, (float)xv.w, acc[3]);
            }
            {
                int sb = __builtin_amdgcn_readfirstlane(sv.y);
                f16x4 xv = *(const f16x4*)(xhh + (size_t)sb * HC + lane * 4);
                acc[0] = fmaf(pv.y, (float)xv.x, acc[0]);
                acc[1] = fmaf(pv.y, (float)xv.y, acc[1]);
                acc[2] = fmaf(pv.y, (float)xv.z, acc[2]);
                acc[3] = fmaf(pv.y, (float)xv.w, acc[3]);
            }
            {
                int sb = __builtin_amdgcn_readfirstlane(sv.z);
                f16x4 xv = *(const f16x4*)(xhh + (size_t)sb * HC + lane * 4);
                acc[0] = fmaf(pv.z, (float)xv.x, acc[0]);
                acc[1] = fmaf(pv.z, (float)xv.y, acc[1]);
                acc[2] = fmaf(pv.z, (float)xv.z, acc[2]);
                acc[3] = fmaf(pv.z, (float)xv.w, acc[3]);
            }
            {
                int sb = __builtin_amdgcn_readfirstlane(sv.w);
                f16x4 xv = *(const f16x4*)(xhh + (size_t)sb * HC + lane * 4);
                acc[0] = fmaf(pv.w, (float)xv.x, acc[0]);
                acc[1] = fmaf(pv.w, (float)xv.y, acc[1]);
                acc[2] = fmaf(pv.w, (float)xv.z, acc[2]);
                acc[3] = fmaf(pv.w, (float)xv.w, acc[3]);
            }
            sv = svn; pv = pvn;
        }
    }

    // every lane of a head-group already holds the full per-head sum
    float rin = 1.f / (psum + 1e-16f);

    float4 bv = *(const float4*)&bias[lane * 4];
    float v0 = acc[0] * rin + bv.x;
    float v1 = acc[1] * rin + bv.y;
    float v2 = acc[2] * rin + bv.z;
    float v3 = acc[3] * rin + bv.w;

    // LayerNorm over 256 channels (wave-wide reduce)
    float s1 = v0 + v1 + v2 + v3;
    float s2 = v0 * v0 + v1 * v1 + v2 * v2 + v3 * v3;
#pragma unroll
    for (int d = 1; d < 64; d <<= 1) {
        s1 += __shfl_xor(s1, d, 64);
        s2 += __shfl_xor(s2, d, 64);
    }
    float mu = s1 * (1.f / 256.f);
    float var = s2 * (1.f / 256.f) - mu * mu;
    float rstd = rsqrtf(var + 1e-5f);
    float4 gv = *(const float4*)&gamma[lane * 4];
    float4 btv = *(const float4*)&beta[lane * 4];
    float y0 = fmaxf((v0 - mu) * rstd * gv.x + btv.x, 0.f);
    float y1 = fmaxf((v1 - mu) * rstd * gv.y + btv.y, 0.f);
    float y2 = fmaxf((v2 - mu) * rstd * gv.z + btv.z, 0.f);
    float y3 = fmaxf((v3 - mu) * rstd * gv.w + btv.w, 0.f);

    // FC 256 -> 10
    float keep = 0.f;
#pragma unroll
    for (int j = 0; j < NCLS; ++j) {
        float4 wv = *(const float4*)&fcWt[j * HC + lane * 4];
        float pj = y0 * wv.x;
        pj = fmaf(y1, wv.y, pj);
        pj = fmaf(y2, wv.z, pj);
        pj = fmaf(y3, wv.w, pj);
#pragma unroll
        for (int d = 1; d < 64; d <<= 1) pj += __shfl_xor(pj, d, 64);
        if (lane == j) keep = pj + fcb[j];
    }
    if (lane < NCLS) out[n * NCLS + lane] = keep;
}

// ---------------------------------------------------------------- launch ----
extern "C" void kernel_launch(void* const* d_in, const int* in_sizes, int n_in,
                              void* d_out, int out_size, void* d_ws, size_t ws_size,
                              hipStream_t stream) {
    const float* x    = (const float*)d_in[0];
    const int*   ei   = (const int*)d_in[1];
    const float* ew   = (const float*)d_in[2];
    const float* W    = (const float*)d_in[3];
    const float* attS = (const float*)d_in[4];
    const float* attD = (const float*)d_in[5];
    const float* attE = (const float*)d_in[6];
    const float* We   = (const float*)d_in[7];
    const float* bias = (const float*)d_in[8];
    const float* gam  = (const float*)d_in[9];
    const float* bet  = (const float*)d_in[10];
    const float* fcW  = (const float*)d_in[11];
    const float* fcb  = (const float*)d_in[12];
    float* out = (float*)d_out;

    const int Nn = in_sizes[0] / HC;       // 50000
    const int E  = in_sizes[1] / 2;        // 800000
    const int* src = ei;
    const int* dst = ei + E;
    const int nb = (Nn + 1023) / 1024;     // 49
    const int EpMax = E + 4 * Nn;          // worst-case padded slots (x4 pad)

    char* ws = (char*)d_ws;
    size_t off = 0;
    auto alloc = [&](size_t bytes) { void* p = ws + off; off = (off + bytes + 255) & ~size_t(255); return p; };
    unsigned short* xhh  = (unsigned short*)alloc((size_t)Nn * HC * 2);
    unsigned short* wt   = (unsigned short*)alloc((size_t)HC * HC * 2);
    float* a_srcb    = (float*)alloc((size_t)Nn * 4 * 4);
    float* a_dstb    = (float*)alloc((size_t)Nn * 4 * 4);
    float* cE        = (float*)alloc(256);
    float* fcWt      = (float*)alloc((size_t)NCLS * HC * 4);
    int*   row_start = (int*)  alloc((size_t)(Nn + 1) * 4);
    int*   deg       = (int*)  alloc((size_t)Nn * 4);
    int*   cursor    = (int*)  alloc((size_t)Nn * 4);
    int*   bsum      = (int*)  alloc((size_t)nb * 4);
    int*   srcs     = (int*)  alloc((size_t)EpMax * 4);    // contiguous with pq
    float* pq       = (float*)alloc((size_t)EpMax * 16);   // [group][h][4]
    (void)ws_size;

    hipMemsetAsync(deg, 0, (size_t)Nn * 4, stream);
    // zero srcs..pq span (pads must read as src=0, p=0)
    size_t zspan = (size_t)((char*)pq - (char*)srcs) + (size_t)EpMax * 16;
    hipMemsetAsync(srcs, 0, zspan, stream);

    prep_kernel<<<267, 256, 0, stream>>>(We, attE, cE, W, wt, fcW, fcWt);

    dim3 g((Nn + 127) / 128, 2);
    gemm_mfma<<<g, 256, 0, stream>>>(x, wt, xhh, Nn);

    attn_coef<<<(Nn + 3) / 4, 256, 0, stream>>>(xhh, attS, attD, a_srcb, a_dstb, Nn);
    hist_kernel<<<(E + 255) / 256, 256, 0, stream>>>(dst, deg, E);
    scan1<<<nb, 1024, 0, stream>>>(deg, row_start, bsum, Nn);
    scan23<<<nb, 1024, 0, stream>>>(row_start, bsum, cursor, Nn, nb);
    scatter_p<<<(E + 255) / 256, 256, 0, stream>>>(src, dst, ew, a_srcb, a_dstb, cE,
                                                   cursor, srcs, pq, E);
    gat_main<<<(Nn + 3) / 4, 256, 0, stream>>>(xhh, row_start, srcs, pq,
                                               bias, gam, bet, fcWt, fcb, out, Nn);
}

// Round 6
// 202.086 us; speedup vs baseline: 1.2868x; 1.0893x over previous
//
#include <hip/hip_runtime.h>
#include <hip/hip_bf16.h>

static constexpr int HEADS = 4;
static constexpr int HID   = 64;
static constexpr int HC    = 256;   // HEADS*HID
static constexpr int NCLS  = 10;

typedef short    bf16x8 __attribute__((ext_vector_type(8)));
typedef _Float16 f16x8  __attribute__((ext_vector_type(8)));
typedef _Float16 f16x4  __attribute__((ext_vector_type(4)));
typedef float    f32x4  __attribute__((ext_vector_type(4)));

__device__ inline unsigned short f2bf(float f) {
    union { float f; unsigned u; } c; c.f = f;
    unsigned r = (c.u + 0x7fff + ((c.u >> 16) & 1)) >> 16;  // RNE
    return (unsigned short)r;
}
__device__ inline unsigned short f2h(float f) {
    _Float16 h = (_Float16)f; unsigned short u; __builtin_memcpy(&u, &h, 2); return u;
}
__device__ inline float h2f(unsigned short u) {
    _Float16 h; __builtin_memcpy(&h, &u, 2); return (float)h;
}

// ------------------------------------------------------------------ prep ----
// b=0: cE; b=1..256: Wt[n][k]=bf16(W[k][n]); b=257..272: fcWh[j][k] (f16, pad)
__global__ void prep_kernel(const float* __restrict__ We, const float* __restrict__ attE,
                            float* __restrict__ cE, const float* __restrict__ W,
                            unsigned short* __restrict__ Wt, const float* __restrict__ fcW,
                            unsigned short* __restrict__ fcWh) {
    int b = blockIdx.x, t = threadIdx.x;
    if (b == 0) {
        float p = We[t] * attE[t];
#pragma unroll
        for (int d = 32; d; d >>= 1) p += __shfl_xor(p, d, 64);
        if ((t & 63) == 0) cE[t >> 6] = p;
    } else if (b <= 256) {
        int k = b - 1;
        Wt[t * 256 + k] = f2bf(W[k * 256 + t]);
    } else {
        int j = b - 257;               // 0..15
        unsigned short v = 0;
        if (j < NCLS) v = f2h(fcW[t * NCLS + j]);
        fcWh[j * 256 + t] = v;
    }
}

// ------------------------------------------------------------ MFMA GEMM -----
// XHh[M,256](f16) = X[M,256](f32) @ Wt^T (bf16 MFMA).
__global__ __launch_bounds__(256) void gemm_mfma(const float* __restrict__ X,
                                                 const unsigned short* __restrict__ Bt,
                                                 unsigned short* __restrict__ XHh, int M) {
    __shared__ alignas(16) unsigned short As[128][40];
    __shared__ alignas(16) unsigned short Bs[128][40];  // Bs[col][k]
    const int tid = threadIdx.x;
    const int lane = tid & 63, wid = tid >> 6;
    const int wr = wid >> 1, wc = wid & 1;
    const int bm = blockIdx.x * 128, bn = blockIdx.y * 128;
    const int fr = lane & 15, kg = lane >> 4;

    f32x4 acc[4][4] = {};

    for (int k0 = 0; k0 < 256; k0 += 32) {
        __syncthreads();
#pragma unroll
        for (int ss = 0; ss < 4; ++ss) {
            int idx = tid + (ss << 8);
            int row = idx >> 3, seg = idx & 7;
            int grow = bm + row;
            float4 av = make_float4(0.f, 0.f, 0.f, 0.f);
            if (grow < M) av = *(const float4*)&X[(size_t)grow * 256 + k0 + seg * 4];
            ushort4 ab = make_ushort4(f2bf(av.x), f2bf(av.y), f2bf(av.z), f2bf(av.w));
            *(ushort4*)&As[row][seg * 4] = ab;
        }
#pragma unroll
        for (int qq = 0; qq < 2; ++qq) {
            int q = tid + (qq << 8);
            int row = q >> 2, part = q & 3;
            const ushort4* bp = (const ushort4*)&Bt[(size_t)(bn + row) * 256 + k0 + part * 8];
            *(ushort4*)&Bs[row][part * 8]     = bp[0];
            *(ushort4*)&Bs[row][part * 8 + 4] = bp[1];
        }
        __syncthreads();

        bf16x8 af[4], bf[4];
#pragma unroll
        for (int i = 0; i < 4; ++i)
            af[i] = *(const bf16x8*)&As[wr * 64 + i * 16 + fr][kg * 8];
#pragma unroll
        for (int j = 0; j < 4; ++j)
            bf[j] = *(const bf16x8*)&Bs[wc * 64 + j * 16 + fr][kg * 8];
#pragma unroll
        for (int i = 0; i < 4; ++i)
#pragma unroll
            for (int j = 0; j < 4; ++j)
                acc[i][j] = __builtin_amdgcn_mfma_f32_16x16x32_bf16(af[i], bf[j], acc[i][j], 0, 0, 0);
    }

    // C/D layout: col = lane&15, row = (lane>>4)*4 + reg
#pragma unroll
    for (int i = 0; i < 4; ++i) {
#pragma unroll
        for (int j = 0; j < 4; ++j) {
            int col = bn + wc * 64 + j * 16 + fr;
#pragma unroll
            for (int r = 0; r < 4; ++r) {
                int row = bm + wr * 64 + i * 16 + kg * 4 + r;
                if (row < M) XHh[(size_t)row * 256 + col] = f2h(acc[i][j][r]);
            }
        }
    }
}

// ------------------------------------------------------- a_src / a_dst ------
__global__ __launch_bounds__(256) void attn_coef(const unsigned short* __restrict__ xhh,
                                                 const float* __restrict__ attS,
                                                 const float* __restrict__ attD,
                                                 float* __restrict__ a_src,
                                                 float* __restrict__ a_dst,
                                                 int Nn) {
    int wid = threadIdx.x >> 6, lane = threadIdx.x & 63;
    int n = blockIdx.x * 4 + wid;
    if (n >= Nn) return;
    ushort4 xv = *(const ushort4*)&xhh[(size_t)n * HC + lane * 4];
    float x0 = h2f(xv.x), x1 = h2f(xv.y), x2 = h2f(xv.z), x3 = h2f(xv.w);
    float4 sv = *(const float4*)&attS[lane * 4];
    float4 dv = *(const float4*)&attD[lane * 4];
    float ps = x0 * sv.x + x1 * sv.y + x2 * sv.z + x3 * sv.w;
    float pd = x0 * dv.x + x1 * dv.y + x2 * dv.z + x3 * dv.w;
#pragma unroll
    for (int d = 1; d < 16; d <<= 1) {
        ps += __shfl_xor(ps, d, 64);
        pd += __shfl_xor(pd, d, 64);
    }
    if ((lane & 15) == 0) {
        a_src[n * 4 + (lane >> 4)] = ps;
        a_dst[n * 4 + (lane >> 4)] = pd;
    }
}

// ------------------------------------------------------------- CSR build ----
// histogram + per-edge rank (position within its dst segment)
__global__ void hist_kernel(const int* __restrict__ dst, int* __restrict__ deg,
                            int* __restrict__ rank, int E) {
    int e = blockIdx.x * 256 + threadIdx.x;
    if (e < E) rank[e] = atomicAdd(&deg[dst[e]], 1);
}

// scan of PADDED degrees (each deg rounded up to x4)
__global__ __launch_bounds__(1024) void scan1(const int* __restrict__ deg,
                                              int* __restrict__ row_start,
                                              int* __restrict__ bsum, int n) {
    __shared__ int wsum[16];
    const int tid = threadIdx.x, lane = tid & 63, wid = tid >> 6;
    int i = blockIdx.x * 1024 + tid;
    int v = (i < n) ? ((deg[i] + 3) & ~3) : 0;
    int incl = v;
#pragma unroll
    for (int d = 1; d < 64; d <<= 1) {
        int t = __shfl_up(incl, d, 64);
        if (lane >= d) incl += t;
    }
    if (lane == 63) wsum[wid] = incl;
    __syncthreads();
    if (tid < 16) {
        int w = wsum[tid];
#pragma unroll
        for (int d = 1; d < 16; d <<= 1) {
            int t = __shfl_up(w, d, 16);
            if (tid >= d) w += t;
        }
        wsum[tid] = w;
    }
    __syncthreads();
    int waveoff = wid ? wsum[wid - 1] : 0;
    if (i < n) row_start[i] = waveoff + incl - v;
    if (tid == 1023) bsum[blockIdx.x] = waveoff + incl;
}

// fused scan2+scan3 (redundant block-sum scan per block)
__global__ __launch_bounds__(1024) void scan23(int* __restrict__ row_start,
                                               const int* __restrict__ bsum, int n, int nb) {
    __shared__ int pref[64];
    const int tid = threadIdx.x;
    if (tid < 64) {
        int v = (tid < nb) ? bsum[tid] : 0;
#pragma unroll
        for (int d = 1; d < 64; d <<= 1) {
            int t = __shfl_up(v, d, 64);
            if (tid >= d) v += t;
        }
        pref[tid] = v;
    }
    __syncthreads();
    int add = blockIdx.x ? pref[blockIdx.x - 1] : 0;
    int i = blockIdx.x * 1024 + tid;
    if (i < n) row_start[i] += add;
    if (i == n) row_start[n] = pref[nb - 1];
}

// ------------------------------------------------------------ scatter+p -----
// pos = row_start[dst] + rank  (no atomics). p layout: pq[group][h][4].
__global__ void scatter_p(const int* __restrict__ src, const int* __restrict__ dst,
                          const float* __restrict__ ew, const float* __restrict__ a_src,
                          const float* __restrict__ a_dst, const float* __restrict__ cE,
                          const int* __restrict__ row_start, const int* __restrict__ rank,
                          int* __restrict__ srcs, float* __restrict__ pq, int E) {
    int e = blockIdx.x * 256 + threadIdx.x;
    if (e >= E) return;
    int s = src[e], d = dst[e];
    float w = ew[e];
    float4 as_ = *(const float4*)&a_src[s * 4];
    float4 ad_ = *(const float4*)&a_dst[d * 4];
    float4 ce  = *(const float4*)cE;
    int pos = row_start[d] + rank[e];
    srcs[pos] = s;
    float al[4] = {as_.x + ad_.x + ce.x * w, as_.y + ad_.y + ce.y * w,
                   as_.z + ad_.z + ce.z * w, as_.w + ad_.w + ce.w * w};
    float* base = pq + ((size_t)(pos >> 2)) * 16 + (pos & 3);
#pragma unroll
    for (int h = 0; h < 4; ++h) {
        float a = al[h] > 0.f ? al[h] : 0.2f * al[h];
        base[h * 4] = __expf(a);           // no max-sub: |alpha| small
    }
}

// ------------------------------------------------------------- main GAT -----
// One WAVE per node. 2-deep software pipeline: compute chunk c while chunk
// c+1's gathers and chunk c+2's meta are in flight. Exact-tail masking (no
// pad zero-fill needed). Output y (post LN+ReLU) in f16; FC is a separate
// MFMA kernel.
__global__ __launch_bounds__(256) void gat_main(
    const unsigned short* __restrict__ xhh, const int* __restrict__ row_start,
    const int* __restrict__ deg, const int* __restrict__ srcs,
    const float* __restrict__ pq, const float* __restrict__ bias,
    const float* __restrict__ gamma, const float* __restrict__ beta,
    unsigned short* __restrict__ yh, int Nn) {
    const int lane = threadIdx.x & 63, wid = threadIdx.x >> 6;
    const int n = blockIdx.x * 4 + wid;
    if (n >= Nn) return;
    const int myh = lane >> 4;
    const int rs = row_start[n];
    const int dn = deg[n];
    const int nfull = dn >> 2, rem = dn & 3;
    const unsigned short* xl = xhh + (size_t)lane * 4;

    f32x4 acc = {0.f, 0.f, 0.f, 0.f};
    float psum = 0.f;

#define LOADMETA(c, S, P)                                                     \
    S = *(const int4*)&srcs[rs + (c) * 4];                                    \
    P = *(const float4*)&pq[((size_t)((rs >> 2) + (c))) * 16 + myh * 4];
#define GATHER(S, X0, X1, X2, X3)                                             \
    X0 = *(const f16x4*)(xl + (size_t)__builtin_amdgcn_readfirstlane((S).x) * HC); \
    X1 = *(const f16x4*)(xl + (size_t)__builtin_amdgcn_readfirstlane((S).y) * HC); \
    X2 = *(const f16x4*)(xl + (size_t)__builtin_amdgcn_readfirstlane((S).z) * HC); \
    X3 = *(const f16x4*)(xl + (size_t)__builtin_amdgcn_readfirstlane((S).w) * HC);
#define COMPUTE(P, X0, X1, X2, X3)                                            \
    psum += ((P).x + (P).y) + ((P).z + (P).w);                                \
    acc[0] = fmaf((P).x, (float)(X0).x, acc[0]);                              \
    acc[1] = fmaf((P).x, (float)(X0).y, acc[1]);                              \
    acc[2] = fmaf((P).x, (float)(X0).z, acc[2]);                              \
    acc[3] = fmaf((P).x, (float)(X0).w, acc[3]);                              \
    acc[0] = fmaf((P).y, (float)(X1).x, acc[0]);                              \
    acc[1] = fmaf((P).y, (float)(X1).y, acc[1]);                              \
    acc[2] = fmaf((P).y, (float)(X1).z, acc[2]);                              \
    acc[3] = fmaf((P).y, (float)(X1).w, acc[3]);                              \
    acc[0] = fmaf((P).z, (float)(X2).x, acc[0]);                              \
    acc[1] = fmaf((P).z, (float)(X2).y, acc[1]);                              \
    acc[2] = fmaf((P).z, (float)(X2).z, acc[2]);                              \
    acc[3] = fmaf((P).z, (float)(X2).w, acc[3]);                              \
    acc[0] = fmaf((P).w, (float)(X3).x, acc[0]);                              \
    acc[1] = fmaf((P).w, (float)(X3).y, acc[1]);                              \
    acc[2] = fmaf((P).w, (float)(X3).z, acc[2]);                              \
    acc[3] = fmaf((P).w, (float)(X3).w, acc[3]);

    if (nfull > 0) {
        int4 s0, sN = {0, 0, 0, 0}, s2 = {0, 0, 0, 0};
        float4 pC, pN = {0.f, 0.f, 0.f, 0.f}, p2 = {0.f, 0.f, 0.f, 0.f};
        f16x4 g0, g1, g2, g3;
        LOADMETA(0, s0, pC);
        GATHER(s0, g0, g1, g2, g3);
        if (nfull > 1) { LOADMETA(1, sN, pN); }
        for (int c = 0; c < nfull; ++c) {
            f16x4 h0, h1, h2, h3;
            if (c + 1 < nfull) { GATHER(sN, h0, h1, h2, h3); }
            if (c + 2 < nfull) { LOADMETA(c + 2, s2, p2); }
            COMPUTE(pC, g0, g1, g2, g3);
            pC = pN; pN = p2; sN = s2;
            g0 = h0; g1 = h1; g2 = h2; g3 = h3;
        }
    }
    if (rem) {
        int4 s; float4 p;
        LOADMETA(nfull, s, p);
        p.w = 0.f;
        if (rem < 3) p.z = 0.f;
        if (rem < 2) p.y = 0.f;
        int b0 = __builtin_amdgcn_readfirstlane(s.x);
        int b1 = rem > 1 ? __builtin_amdgcn_readfirstlane(s.y) : b0;
        int b2 = rem > 2 ? __builtin_amdgcn_readfirstlane(s.z) : b0;
        f16x4 x0 = *(const f16x4*)(xl + (size_t)b0 * HC);
        f16x4 x1 = *(const f16x4*)(xl + (size_t)b1 * HC);
        f16x4 x2 = *(const f16x4*)(xl + (size_t)b2 * HC);
        COMPUTE(p, x0, x1, x2, x0);     // w-slot: p.w==0
    }
#undef LOADMETA
#undef GATHER
#undef COMPUTE

    // every lane of a head-group already holds the full per-head sum
    float rin = 1.f / (psum + 1e-16f);

    float4 bv = *(const float4*)&bias[lane * 4];
    float v0 = acc[0] * rin + bv.x;
    float v1 = acc[1] * rin + bv.y;
    float v2 = acc[2] * rin + bv.z;
    float v3 = acc[3] * rin + bv.w;

    // LayerNorm over 256 channels (wave-wide reduce)
    float s1 = v0 + v1 + v2 + v3;
    float s2v = v0 * v0 + v1 * v1 + v2 * v2 + v3 * v3;
#pragma unroll
    for (int d = 1; d < 64; d <<= 1) {
        s1 += __shfl_xor(s1, d, 64);
        s2v += __shfl_xor(s2v, d, 64);
    }
    float mu = s1 * (1.f / 256.f);
    float var = s2v * (1.f / 256.f) - mu * mu;
    float rstd = rsqrtf(var + 1e-5f);
    float4 gv = *(const float4*)&gamma[lane * 4];
    float4 btv = *(const float4*)&beta[lane * 4];
    float y0 = fmaxf((v0 - mu) * rstd * gv.x + btv.x, 0.f);
    float y1 = fmaxf((v1 - mu) * rstd * gv.y + btv.y, 0.f);
    float y2 = fmaxf((v2 - mu) * rstd * gv.z + btv.z, 0.f);
    float y3 = fmaxf((v3 - mu) * rstd * gv.w + btv.w, 0.f);

    f16x4 yv;
    yv.x = (_Float16)y0; yv.y = (_Float16)y1; yv.z = (_Float16)y2; yv.w = (_Float16)y3;
    *(f16x4*)&yh[(size_t)n * HC + lane * 4] = yv;
}

// ------------------------------------------------------------ FC (MFMA) -----
// out[M,10] = y[M,256](f16) @ fcWh^T(f16,[16][256]) + fcb. 4 waves x 64 rows.
__global__ __launch_bounds__(256) void fc_gemm(const unsigned short* __restrict__ yh,
                                               const unsigned short* __restrict__ fcWh,
                                               const float* __restrict__ fcb,
                                               float* __restrict__ out, int M) {
    const int lane = threadIdx.x & 63, wid = threadIdx.x >> 6;
    const int rowbase = blockIdx.x * 256 + wid * 64;
    const int fr = lane & 15, kg = lane >> 4;
    f32x4 acc[4] = {};
#pragma unroll
    for (int k0 = 0; k0 < 256; k0 += 32) {
        f16x8 bfr = *(const f16x8*)&fcWh[fr * 256 + k0 + kg * 8];
#pragma unroll
        for (int i = 0; i < 4; ++i) {
            int row = rowbase + i * 16 + fr;
            f16x8 afr = {};
            if (row < M) afr = *(const f16x8*)&yh[(size_t)row * 256 + k0 + kg * 8];
            acc[i] = __builtin_amdgcn_mfma_f32_16x16x32_f16(afr, bfr, acc[i], 0, 0, 0);
        }
    }
    if (fr < NCLS) {
        float bb = fcb[fr];
#pragma unroll
        for (int i = 0; i < 4; ++i) {
#pragma unroll
            for (int r = 0; r < 4; ++r) {
                int row = rowbase + i * 16 + kg * 4 + r;
                if (row < M) out[(size_t)row * NCLS + fr] = acc[i][r] + bb;
            }
        }
    }
}

// ---------------------------------------------------------------- launch ----
extern "C" void kernel_launch(void* const* d_in, const int* in_sizes, int n_in,
                              void* d_out, int out_size, void* d_ws, size_t ws_size,
                              hipStream_t stream) {
    const float* x    = (const float*)d_in[0];
    const int*   ei   = (const int*)d_in[1];
    const float* ew   = (const float*)d_in[2];
    const float* W    = (const float*)d_in[3];
    const float* attS = (const float*)d_in[4];
    const float* attD = (const float*)d_in[5];
    const float* attE = (const float*)d_in[6];
    const float* We   = (const float*)d_in[7];
    const float* bias = (const float*)d_in[8];
    const float* gam  = (const float*)d_in[9];
    const float* bet  = (const float*)d_in[10];
    const float* fcW  = (const float*)d_in[11];
    const float* fcb  = (const float*)d_in[12];
    float* out = (float*)d_out;

    const int Nn = in_sizes[0] / HC;       // 50000
    const int E  = in_sizes[1] / 2;        // 800000
    const int* src = ei;
    const int* dst = ei + E;
    const int nb = (Nn + 1023) / 1024;     // 49
    const int EpMax = E + 4 * Nn;          // worst-case padded slots (x4 pad)

    char* ws = (char*)d_ws;
    size_t off = 0;
    auto alloc = [&](size_t bytes) { void* p = ws + off; off = (off + bytes + 255) & ~size_t(255); return p; };
    unsigned short* xhh  = (unsigned short*)alloc((size_t)Nn * HC * 2);
    unsigned short* yh   = (unsigned short*)alloc((size_t)Nn * HC * 2);
    unsigned short* wt   = (unsigned short*)alloc((size_t)HC * HC * 2);
    unsigned short* fcWh = (unsigned short*)alloc((size_t)16 * HC * 2);
    float* a_srcb    = (float*)alloc((size_t)Nn * 4 * 4);
    float* a_dstb    = (float*)alloc((size_t)Nn * 4 * 4);
    float* cE        = (float*)alloc(256);
    int*   row_start = (int*)  alloc((size_t)(Nn + 1) * 4);
    int*   deg       = (int*)  alloc((size_t)Nn * 4);
    int*   bsum      = (int*)  alloc((size_t)nb * 4);
    int*   rank      = (int*)  alloc((size_t)E * 4);
    int*   srcs      = (int*)  alloc((size_t)EpMax * 4);
    float* pq        = (float*)alloc((size_t)EpMax * 16);   // [group][h][4]
    (void)ws_size;

    hipMemsetAsync(deg, 0, (size_t)Nn * 4, stream);

    prep_kernel<<<273, 256, 0, stream>>>(We, attE, cE, W, wt, fcW, fcWh);

    dim3 g((Nn + 127) / 128, 2);
    gemm_mfma<<<g, 256, 0, stream>>>(x, wt, xhh, Nn);

    attn_coef<<<(Nn + 3) / 4, 256, 0, stream>>>(xhh, attS, attD, a_srcb, a_dstb, Nn);
    hist_kernel<<<(E + 255) / 256, 256, 0, stream>>>(dst, deg, rank, E);
    scan1<<<nb, 1024, 0, stream>>>(deg, row_start, bsum, Nn);
    scan23<<<nb, 1024, 0, stream>>>(row_start, bsum, Nn, nb);
    scatter_p<<<(E + 255) / 256, 256, 0, stream>>>(src, dst, ew, a_srcb, a_dstb, cE,
                                                   row_start, rank, srcs, pq, E);
    gat_main<<<(Nn + 3) / 4, 256, 0, stream>>>(xhh, row_start, deg, srcs, pq,
                                               bias, gam, bet, yh, Nn);
    fc_gemm<<<(Nn + 255) / 256, 256, 0, stream>>>(yh, fcWh, fcb, out, Nn);
}